// Round 5
// baseline (2546.920 us; speedup 1.0000x reference)
//
#include <hip/hip_runtime.h>

#define T_SEQ 200
#define NB    32
#define NE    300
#define NH    1000
#define NK    9
#define HP    1024          // padded hidden stride (elements)
#define NJ    4032          // xg rows per t: 4 gates * 1008 padded units
#define RW    1008          // padded units
#define EPD   320           // padded embed K
#define WS_LD 1032          // LDS W row stride

typedef __attribute__((ext_vector_type(4))) float f32x4;
typedef __attribute__((ext_vector_type(8))) short s16x8;
typedef __attribute__((ext_vector_type(4))) short s16x4;
typedef unsigned long long u64;

__device__ __forceinline__ unsigned short f2bf(float f) {
    union { float f; unsigned u; } v; v.f = f;
    unsigned r = v.u + 0x7FFFu + ((v.u >> 16) & 1u);   // RNE
    return (unsigned short)(r >> 16);
}
__device__ __forceinline__ float bf2f(unsigned short h) {
    union { unsigned u; float f; } v; v.u = ((unsigned)h) << 16;
    return v.f;
}
__device__ __forceinline__ float ftanh(float x) {
    float e = __expf(fminf(2.f * x, 80.f));
    return (e - 1.f) / (e + 1.f);
}
__device__ __forceinline__ float fsig(float x) {
    return 1.f / (1.f + __expf(-x));
}

// ---------------------------------------------------------------------------
// prep_emb: gather+convert embeds -> bf16 [t*32+b][320]; block 0 zeroes flags
// ---------------------------------------------------------------------------
__global__ __launch_bounds__(256) void prep_emb(
    const int* __restrict__ x, const float* __restrict__ embed_w,
    unsigned short* __restrict__ emb_bf, unsigned* __restrict__ flags)
{
    const int t = blockIdx.x, tid = threadIdx.x;
    if (blockIdx.x == 0) {
        for (int i = tid; i < 2048; i += 256) flags[i] = 0;
    }
    for (int idx = tid; idx < NB * EPD; idx += 256) {
        int b = idx / EPD, e = idx - b * EPD;
        float v = (e < NE) ? embed_w[(size_t)x[t * NB + b] * NE + e] : 0.f;
        emb_bf[((size_t)t * NB + b) * EPD + e] = f2bf(v);
    }
}

// ---------------------------------------------------------------------------
// prep_w: W_ih -> bf16 [j'][320] with j' = q*1008+m; bias[j'] = b_ih+b_hh
// ---------------------------------------------------------------------------
__global__ __launch_bounds__(256) void prep_w(
    const float* __restrict__ W_ih, const float* __restrict__ b_ih,
    const float* __restrict__ b_hh, unsigned short* __restrict__ wih_bf,
    float* __restrict__ biasg)
{
    const int wgi = blockIdx.x, tid = threadIdx.x;   // 63 blocks x 64 rows
    for (int idx = tid; idx < 64 * EPD; idx += 256) {
        int jr = idx / EPD, e = idx - jr * EPD;
        int jp = wgi * 64 + jr;
        int q = jp / RW, m = jp - q * RW;
        float v = (m < NH && e < NE) ? W_ih[(size_t)(q * NH + m) * NE + e] : 0.f;
        wih_bf[(size_t)jp * EPD + e] = f2bf(v);
    }
    if (tid < 64) {
        int jp = wgi * 64 + tid;
        int q = jp / RW, m = jp - q * RW;
        biasg[jp] = (m < NH) ? (b_ih[q * NH + m] + b_hh[q * NH + m]) : 0.f;
    }
}

// ---------------------------------------------------------------------------
// proj: xg[t][j'][b] = emb . W_ih^T + bias   (pure MFMA, no LDS)
// ---------------------------------------------------------------------------
__global__ __launch_bounds__(256) void proj_kernel(
    const unsigned short* __restrict__ emb_bf,
    const unsigned short* __restrict__ wih_bf,
    const float* __restrict__ biasg, unsigned short* __restrict__ xg)
{
    const int jt = blockIdx.x, t = blockIdx.y, tid = threadIdx.x;
    const int w = tid >> 6, lane = tid & 63;
    const int col = lane & 15, quad = lane >> 4;

    const unsigned short* eb = emb_bf + (size_t)t * NB * EPD;
    const unsigned short* wb = wih_bf + (size_t)(jt * 64 + w * 16 + col) * EPD;
    const unsigned short* ea0 = eb + (size_t)col * EPD;
    const unsigned short* ea1 = eb + (size_t)(16 + col) * EPD;

    f32x4 acc0 = {0.f, 0.f, 0.f, 0.f};
    f32x4 acc1 = {0.f, 0.f, 0.f, 0.f};
#pragma unroll
    for (int kc = 0; kc < EPD / 32; ++kc) {
        int ko = kc * 32 + quad * 8;
        s16x8 a0 = *(const s16x8*)&ea0[ko];
        s16x8 a1 = *(const s16x8*)&ea1[ko];
        s16x8 bb = *(const s16x8*)&wb[ko];
        acc0 = __builtin_amdgcn_mfma_f32_16x16x32_bf16(a0, bb, acc0, 0, 0, 0);
        acc1 = __builtin_amdgcn_mfma_f32_16x16x32_bf16(a1, bb, acc1, 0, 0, 0);
    }
    const int jp = jt * 64 + w * 16 + col;
    const float bi = biasg[jp];
    size_t base = ((size_t)t * NJ + jp) * NB;
    s16x4 p0, p1;
#pragma unroll
    for (int r = 0; r < 4; ++r) {
        p0[r] = (short)f2bf(acc0[r] + bi);
        p1[r] = (short)f2bf(acc1[r] + bi);
    }
    *(s16x4*)&xg[base + quad * 4]      = p0;
    *(s16x4*)&xg[base + 16 + quad * 4] = p1;
}

// ---------------------------------------------------------------------------
// fence-free flag barrier: all h traffic is agent-relaxed-atomic (L2-bypass),
// so no cache maintenance needed. __syncthreads drains vmcnt (stores LLC-ack'd)
// before tid0 publishes; workgroup acquire fence only for compile-order.
// ---------------------------------------------------------------------------
__device__ __forceinline__ void gbar2(unsigned* flags, unsigned phase) {
    __syncthreads();   // all waves' stores vmcnt-drained (LLC-acknowledged)
    const int tid = threadIdx.x;
    if (tid < 64) {
        if (tid == 0) {
            __hip_atomic_store(&flags[blockIdx.x * 32], phase,
                               __ATOMIC_RELAXED, __HIP_MEMORY_SCOPE_AGENT);
        }
        bool done;
        do {
            unsigned v = (tid < 63)
                ? __hip_atomic_load(&flags[tid * 32], __ATOMIC_RELAXED,
                                    __HIP_MEMORY_SCOPE_AGENT)
                : phase;
            done = (bool)__all((int)(v >= phase));
            if (!done) __builtin_amdgcn_s_sleep(1);
        } while (!done);
    }
    __syncthreads();
    __builtin_amdgcn_fence(__ATOMIC_ACQUIRE, "workgroup");  // order-only, no cache inv
}

// ---------------------------------------------------------------------------
// lstm (cooperative): 63 WGs x 256 thr. WG wg owns units [16wg,16wg+16).
// Wave w: batch-half bh=w&1, gate pair q0=2*(w>>1), q1=q0+1.
// W_hh (64 rows x 1024) bf16 in LDS. h via agent-relaxed atomics (L2-bypass).
// ---------------------------------------------------------------------------
__global__ __launch_bounds__(256, 1) void lstm_kernel(
    const float* __restrict__ W_hh,
    const unsigned short* __restrict__ xg,
    unsigned short* __restrict__ hs,
    unsigned* __restrict__ flags)
{
    __shared__ __align__(16) unsigned short s_w[64 * WS_LD];   // 132,096 B
    __shared__ float s_g[64 * 36];                             //   9,216 B

    const int wg = blockIdx.x, tid = threadIdx.x;
    const int w = tid >> 6, lane = tid & 63;
    const int col = lane & 15, quad = lane >> 4;
    const int bh = w & 1, q0 = (w >> 1) * 2, q1 = q0 + 1;
    unsigned* hs32 = (unsigned*)hs;

    // stage W_hh rows -> LDS bf16 (row r = q*16+n -> W_hh[q*1000 + wg*16+n])
    for (int idx = tid; idx < 64 * WS_LD; idx += 256) {
        int r = idx / WS_LD, k = idx - r * WS_LD;
        int q = r >> 4, m = wg * 16 + (r & 15);
        float v = (k < NH && m < NH) ? W_hh[(size_t)(q * NH + m) * NH + k] : 0.f;
        s_w[idx] = f2bf(v);
    }
    // zero h0 slice via atomic stores (must be LLC-visible without fences)
    {
        int b = tid >> 3, v = tid & 7;
        __hip_atomic_store(&hs32[(size_t)b * (HP / 2) + wg * 8 + v], 0u,
                           __ATOMIC_RELAXED, __HIP_MEMORY_SCOPE_AGENT);
        if (wg == 62)
            __hip_atomic_store(&hs32[(size_t)b * (HP / 2) + 504 + v], 0u,
                               __ATOMIC_RELAXED, __HIP_MEMORY_SCOPE_AGENT);
    }
    gbar2(flags, 1u);

    const unsigned short* wb0 = s_w + (size_t)(q0 * 16 + col) * WS_LD;
    const unsigned short* wb1 = s_w + (size_t)(q1 * 16 + col) * WS_LD;
    const int v_ep = tid >> 5;          // 0..7: unit pair (2v, 2v+1)
    const int b_ep = tid & 31;
    float c0 = 0.f, c1 = 0.f;

    for (int t = 0; t < T_SEQ; ++t) {
        const unsigned short* hp = hs + (size_t)t * NB * HP + (size_t)(bh * 16 + col) * HP;
        // xg contributions are barrier-independent: issue early (plain loads, L2-warm)
        const s16x4 x0 = *(const s16x4*)&xg[((size_t)t * NJ + q0 * RW + wg * 16 + col) * NB
                                           + bh * 16 + quad * 4];
        const s16x4 x1 = *(const s16x4*)&xg[((size_t)t * NJ + q1 * RW + wg * 16 + col) * NB
                                           + bh * 16 + quad * 4];
        f32x4 A0 = {0.f, 0.f, 0.f, 0.f};
        f32x4 A1 = {0.f, 0.f, 0.f, 0.f};
#pragma unroll 16
        for (int kc = 0; kc < 32; ++kc) {
            int ko = kc * 32 + quad * 8;
            union { u64 q[2]; s16x8 v; } ua;
            ua.q[0] = __hip_atomic_load((const u64*)(hp + ko), __ATOMIC_RELAXED,
                                        __HIP_MEMORY_SCOPE_AGENT);
            ua.q[1] = __hip_atomic_load((const u64*)(hp + ko + 4), __ATOMIC_RELAXED,
                                        __HIP_MEMORY_SCOPE_AGENT);
            s16x8 b0 = *(const s16x8*)&wb0[ko];
            s16x8 b1 = *(const s16x8*)&wb1[ko];
            A0 = __builtin_amdgcn_mfma_f32_16x16x32_bf16(ua.v, b0, A0, 0, 0, 0);
            A1 = __builtin_amdgcn_mfma_f32_16x16x32_bf16(ua.v, b1, A1, 0, 0, 0);
        }
#pragma unroll
        for (int r = 0; r < 4; ++r) {
            s_g[(q0 * 16 + col) * 36 + bh * 16 + quad * 4 + r] = A0[r] + bf2f((unsigned short)x0[r]);
            s_g[(q1 * 16 + col) * 36 + bh * 16 + quad * 4 + r] = A1[r] + bf2f((unsigned short)x1[r]);
        }
        __syncthreads();
        // epilogue: thread handles units (2v, 2v+1) for batch b_ep; pack 2 bf16
        {
            int u0 = 2 * v_ep, u1 = 2 * v_ep + 1;
            float gi0 = s_g[(0 * 16 + u0) * 36 + b_ep];
            float gf0 = s_g[(1 * 16 + u0) * 36 + b_ep];
            float gg0 = s_g[(2 * 16 + u0) * 36 + b_ep];
            float go0 = s_g[(3 * 16 + u0) * 36 + b_ep];
            float gi1 = s_g[(0 * 16 + u1) * 36 + b_ep];
            float gf1 = s_g[(1 * 16 + u1) * 36 + b_ep];
            float gg1 = s_g[(2 * 16 + u1) * 36 + b_ep];
            float go1 = s_g[(3 * 16 + u1) * 36 + b_ep];
            c0 = fsig(gf0) * c0 + fsig(gi0) * ftanh(gg0);
            c1 = fsig(gf1) * c1 + fsig(gi1) * ftanh(gg1);
            float h0 = fsig(go0) * ftanh(c0);
            float h1 = fsig(go1) * ftanh(c1);
            unsigned pack = (unsigned)f2bf(h0) | ((unsigned)f2bf(h1) << 16);
            __hip_atomic_store(&hs32[((size_t)(t + 1) * NB + b_ep) * (HP / 2) + wg * 8 + v_ep],
                               pack, __ATOMIC_RELAXED, __HIP_MEMORY_SCOPE_AGENT);
        }
        if (t < T_SEQ - 1) gbar2(flags, (unsigned)(t + 2));
    }
}

// ---------------------------------------------------------------------------
// tag_kernel: tag_space + log_softmax over BATCH axis -> em[t][b][k] (f32)
// ---------------------------------------------------------------------------
__global__ __launch_bounds__(320) void tag_kernel(
    const unsigned short* __restrict__ hs, const float* __restrict__ lin_w,
    const float* __restrict__ lin_b, float* __restrict__ em)
{
    __shared__ float s_lin[NH * NK];
    __shared__ float s_ts[NB * NK];
    __shared__ float s_lse[NK];
    const int t = blockIdx.x, tid = threadIdx.x;
    for (int idx = tid; idx < NH * NK; idx += 320) {
        int e = idx / NK, k = idx - e * NK;
        s_lin[idx] = lin_w[(size_t)k * NH + e];
    }
    __syncthreads();
    if (tid < NB * NK) {
        int b = tid / NK, k = tid - b * NK;
        const unsigned short* hrow = hs + ((size_t)(t + 1) * NB + b) * HP;
        float acc = lin_b[k];
#pragma unroll 4
        for (int e = 0; e < NH; ++e)
            acc += bf2f(hrow[e]) * s_lin[e * NK + k];
        s_ts[b * NK + k] = acc;
    }
    __syncthreads();
    if (tid < NK) {
        float m = -1e30f;
        for (int b = 0; b < NB; ++b) m = fmaxf(m, s_ts[b * NK + tid]);
        float s = 0.f;
        for (int b = 0; b < NB; ++b) s += __expf(s_ts[b * NK + tid] - m);
        s_lse[tid] = m + __logf(s);
    }
    __syncthreads();
    if (tid < NB * NK) {
        int b = tid / NK, k = tid - b * NK;
        em[((size_t)t * NB + b) * NK + k] = s_ts[b * NK + k] - s_lse[k];
    }
}

// ---------------------------------------------------------------------------
// crf_kernel: numerator + alpha recursion + reduction -> out[0]
// ---------------------------------------------------------------------------
__global__ __launch_bounds__(320) void crf_kernel(
    const int* __restrict__ y, const float* __restrict__ em,
    const float* __restrict__ start_trans, const float* __restrict__ end_trans,
    const float* __restrict__ trans, float* __restrict__ out)
{
    __shared__ float s_trans[NK * NK];
    __shared__ float s_alpha[NB * NK];
    __shared__ float s_red[NB];
    const int tid = threadIdx.x;
    if (tid < NK * NK) s_trans[tid] = trans[tid];
    __syncthreads();

    float num = 0.f;
    if (tid < NB) {
        int b = tid, yp = y[b];
        num = start_trans[yp] + em[(size_t)b * NK + yp];
        for (int t = 1; t < T_SEQ; ++t) {
            int yc = y[t * NB + b];
            num += s_trans[yp * NK + yc] + em[((size_t)t * NB + b) * NK + yc];
            yp = yc;
        }
        num += end_trans[yp];
    }

    const int b = tid / NK, k = tid - (tid / NK) * NK;
    if (tid < NB * NK)
        s_alpha[tid] = start_trans[k] + em[(size_t)b * NK + k];
    __syncthreads();

    for (int t = 1; t < T_SEQ; ++t) {
        float nv = 0.f;
        if (tid < NB * NK) {
            float m = -1e30f;
#pragma unroll
            for (int i = 0; i < NK; ++i)
                m = fmaxf(m, s_alpha[b * NK + i] + s_trans[i * NK + k]);
            float s = 0.f;
#pragma unroll
            for (int i = 0; i < NK; ++i)
                s += __expf(s_alpha[b * NK + i] + s_trans[i * NK + k] - m);
            nv = em[((size_t)t * NB + b) * NK + k] + m + __logf(s);
        }
        __syncthreads();
        if (tid < NB * NK) s_alpha[tid] = nv;
        __syncthreads();
    }

    if (tid < NB) {
        float m = -1e30f;
        for (int k2 = 0; k2 < NK; ++k2)
            m = fmaxf(m, s_alpha[tid * NK + k2] + end_trans[k2]);
        float s = 0.f;
        for (int k2 = 0; k2 < NK; ++k2)
            s += __expf(s_alpha[tid * NK + k2] + end_trans[k2] - m);
        s_red[tid] = num - (m + __logf(s));
    }
    __syncthreads();
    if (tid == 0) {
        float tot = 0.f;
        for (int i = 0; i < NB; ++i) tot += s_red[i];
        out[0] = tot;
    }
}

// ---------------------------------------------------------------------------
extern "C" void kernel_launch(void* const* d_in, const int* in_sizes, int n_in,
                              void* d_out, int out_size, void* d_ws, size_t ws_size,
                              hipStream_t stream)
{
    const int*   x           = (const int*)d_in[0];
    const int*   y           = (const int*)d_in[1];
    const float* embed_w     = (const float*)d_in[2];
    const float* W_ih        = (const float*)d_in[3];
    const float* W_hh        = (const float*)d_in[4];
    const float* b_ih        = (const float*)d_in[5];
    const float* b_hh        = (const float*)d_in[6];
    const float* lin_w       = (const float*)d_in[7];
    const float* lin_b       = (const float*)d_in[8];
    const float* start_trans = (const float*)d_in[9];
    const float* end_trans   = (const float*)d_in[10];
    const float* trans       = (const float*)d_in[11];
    float* out = (float*)d_out;

    char* ws = (char*)d_ws;
    unsigned short* xg     = (unsigned short*)(ws);               // 51,609,600 B
    unsigned short* hs     = (unsigned short*)(ws + 51609600);    // 13,172,736 B
    float*          em     = (float*)(ws + 64782336);             //    230,400 B
    unsigned short* emb_bf = (unsigned short*)(ws + 65012736);    //  4,096,000 B
    unsigned short* wih_bf = (unsigned short*)(ws + 69108736);    //  2,580,480 B
    float*          biasg  = (float*)(ws + 71689216);             //     16,128 B
    unsigned*       flags  = (unsigned*)(ws + 71705344);          //      8,192 B

    prep_emb<<<dim3(T_SEQ), 256, 0, stream>>>(x, embed_w, emb_bf, flags);
    prep_w<<<dim3(63), 256, 0, stream>>>(W_ih, b_ih, b_hh, wih_bf, biasg);
    proj_kernel<<<dim3(63, T_SEQ), 256, 0, stream>>>(emb_bf, wih_bf, biasg, xg);

    const float* a0 = W_hh;
    const unsigned short* a1 = xg;
    unsigned short* a2 = hs;
    unsigned* a3 = flags;
    void* args[] = { (void*)&a0, (void*)&a1, (void*)&a2, (void*)&a3 };
    hipLaunchCooperativeKernel((const void*)lstm_kernel, dim3(63), dim3(256),
                               args, 0, stream);

    tag_kernel<<<dim3(T_SEQ), 320, 0, stream>>>(hs, lin_w, lin_b, em);
    crf_kernel<<<dim3(1), 320, 0, stream>>>(y, em, start_trans, end_trans, trans, out);
}

// Round 6
// 2119.984 us; speedup vs baseline: 1.2014x; 1.2014x over previous
//
#include <hip/hip_runtime.h>

#define T_SEQ 200
#define NB    32
#define NE    300
#define NH    1000
#define NK    9
#define HP    1024          // hs row stride (elements, bf16) for tag_kernel
#define NJ    4096          // xg rows per t: 32 wgu * 128
#define EPD   320           // padded embed K
#define KHQ   1024          // h_q row stride bytes (fp8 units)
#define WSCALE 256.0f
#define HSCALE 16.0f
#define GSCALE (1.0f / (256.0f * 16.0f))

typedef __attribute__((ext_vector_type(4))) float f32x4;
typedef __attribute__((ext_vector_type(8))) short s16x8;
typedef __attribute__((ext_vector_type(4))) short s16x4;
typedef __attribute__((ext_vector_type(4))) float floatx4;
typedef unsigned long long u64;
typedef unsigned int u32;

__device__ __forceinline__ unsigned short f2bf(float f) {
    union { float f; unsigned u; } v; v.f = f;
    unsigned r = v.u + 0x7FFFu + ((v.u >> 16) & 1u);   // RNE
    return (unsigned short)(r >> 16);
}
__device__ __forceinline__ float bf2f(unsigned short h) {
    union { unsigned u; float f; } v; v.u = ((unsigned)h) << 16;
    return v.f;
}
__device__ __forceinline__ float ftanh(float x) {
    float e = __expf(fminf(2.f * x, 80.f));
    return (e - 1.f) / (e + 1.f);
}
__device__ __forceinline__ float fsig(float x) {
    return 1.f / (1.f + __expf(-x));
}

// ---------------------------------------------------------------------------
// prep_emb: gather+convert embeds -> bf16 [t*32+b][320]; block 0 zeroes flags
// ---------------------------------------------------------------------------
__global__ __launch_bounds__(256) void prep_emb(
    const int* __restrict__ x, const float* __restrict__ embed_w,
    unsigned short* __restrict__ emb_bf, unsigned* __restrict__ flags)
{
    const int t = blockIdx.x, tid = threadIdx.x;
    if (blockIdx.x == 0) {
        for (int i = tid; i < 2048; i += 256) flags[i] = 0;
    }
    for (int idx = tid; idx < NB * EPD; idx += 256) {
        int b = idx / EPD, e = idx - b * EPD;
        float v = (e < NE) ? embed_w[(size_t)x[t * NB + b] * NE + e] : 0.f;
        emb_bf[((size_t)t * NB + b) * EPD + e] = f2bf(v);
    }
}

// ---------------------------------------------------------------------------
// prep_w: W_ih -> bf16 [jp][320]; jp = wgu*128 + g*32 + uu; m = wgu*32+uu
// bias[jp] = b_ih+b_hh (0 for pad rows m>=1000)
// ---------------------------------------------------------------------------
__global__ __launch_bounds__(256) void prep_w(
    const float* __restrict__ W_ih, const float* __restrict__ b_ih,
    const float* __restrict__ b_hh, unsigned short* __restrict__ wih_bf,
    float* __restrict__ biasg)
{
    const int blk = blockIdx.x, tid = threadIdx.x;   // 64 blocks x 64 rows
    for (int idx = tid; idx < 64 * EPD; idx += 256) {
        int jr = idx / EPD, e = idx - jr * EPD;
        int jp = blk * 64 + jr;
        int wgu = jp >> 7, rr = jp & 127, g = rr >> 5, uu = rr & 31;
        int m = wgu * 32 + uu;
        float v = (m < NH && e < NE) ? W_ih[(size_t)(g * NH + m) * NE + e] : 0.f;
        wih_bf[(size_t)jp * EPD + e] = f2bf(v);
    }
    if (tid < 64) {
        int jp = blk * 64 + tid;
        int wgu = jp >> 7, rr = jp & 127, g = rr >> 5, uu = rr & 31;
        int m = wgu * 32 + uu;
        biasg[jp] = (m < NH) ? (b_ih[g * NH + m] + b_hh[g * NH + m]) : 0.f;
    }
}

// ---------------------------------------------------------------------------
// proj: xg[t][jp][b] = emb . W_ih^T + bias   (pure MFMA, no LDS)
// ---------------------------------------------------------------------------
__global__ __launch_bounds__(256) void proj_kernel(
    const unsigned short* __restrict__ emb_bf,
    const unsigned short* __restrict__ wih_bf,
    const float* __restrict__ biasg, unsigned short* __restrict__ xg)
{
    const int jt = blockIdx.x, t = blockIdx.y, tid = threadIdx.x;
    const int w = tid >> 6, lane = tid & 63;
    const int col = lane & 15, quad = lane >> 4;

    const unsigned short* eb = emb_bf + (size_t)t * NB * EPD;
    const unsigned short* wb = wih_bf + (size_t)(jt * 64 + w * 16 + col) * EPD;
    const unsigned short* ea0 = eb + (size_t)col * EPD;
    const unsigned short* ea1 = eb + (size_t)(16 + col) * EPD;

    f32x4 acc0 = {0.f, 0.f, 0.f, 0.f};
    f32x4 acc1 = {0.f, 0.f, 0.f, 0.f};
#pragma unroll
    for (int kc = 0; kc < EPD / 32; ++kc) {
        int ko = kc * 32 + quad * 8;
        s16x8 a0 = *(const s16x8*)&ea0[ko];
        s16x8 a1 = *(const s16x8*)&ea1[ko];
        s16x8 bb = *(const s16x8*)&wb[ko];
        acc0 = __builtin_amdgcn_mfma_f32_16x16x32_bf16(a0, bb, acc0, 0, 0, 0);
        acc1 = __builtin_amdgcn_mfma_f32_16x16x32_bf16(a1, bb, acc1, 0, 0, 0);
    }
    const int jp = jt * 64 + w * 16 + col;
    const float bi = biasg[jp];
    size_t base = ((size_t)t * NJ + jp) * NB;
    s16x4 p0, p1;
#pragma unroll
    for (int r = 0; r < 4; ++r) {
        p0[r] = (short)f2bf(acc0[r] + bi);
        p1[r] = (short)f2bf(acc1[r] + bi);
    }
    *(s16x4*)&xg[base + quad * 4]      = p0;
    *(s16x4*)&xg[base + 16 + quad * 4] = p1;
}

// ---------------------------------------------------------------------------
// flag barrier over 32 WGs: flags compact (32 u32 = 2 lines); agent-relaxed.
// __syncthreads drains vmcnt (h stores LLC-ack'd) before publish.
// ---------------------------------------------------------------------------
__device__ __forceinline__ void gbar(unsigned* flags, unsigned phase) {
    __syncthreads();
    const int tid = threadIdx.x;
    if (tid < 64) {
        if (tid == 0)
            __hip_atomic_store(&flags[blockIdx.x], phase,
                               __ATOMIC_RELAXED, __HIP_MEMORY_SCOPE_AGENT);
        bool done;
        do {
            unsigned v = (tid < 32)
                ? __hip_atomic_load(&flags[tid], __ATOMIC_RELAXED,
                                    __HIP_MEMORY_SCOPE_AGENT)
                : phase;
            done = (bool)__all((int)(v >= phase));
            if (!done) __builtin_amdgcn_s_sleep(1);
        } while (!done);
    }
    __syncthreads();
    __builtin_amdgcn_fence(__ATOMIC_ACQUIRE, "workgroup");  // order-only
}

// ---------------------------------------------------------------------------
// lstm: 32 WGs x 256 thr. WG wg owns units [32wg, 32wg+32) (1024-unit pad).
// W_hh fp8(e4m3, x256) in LDS, XOR-swizzled (conflict-free ds_read_b64).
// h fp8(x16) in global (h_q), exchanged via agent-relaxed atomics (LLC).
// Wave w: bh = w>>1 (batch half), p = w&1 (unit half); lane owns all 4 gates
// of 4 cells (b = bh*16+quad*4+r, u = 32wg+16p+col) -> intra-lane epilogue.
// ---------------------------------------------------------------------------
__global__ __launch_bounds__(256, 1) void lstm_kernel(
    const float* __restrict__ W_hh,
    const unsigned short* __restrict__ xg,
    unsigned short* __restrict__ hs,
    unsigned char* __restrict__ h_q,
    unsigned* __restrict__ flags)
{
    __shared__ __align__(16) unsigned char s_w[128 * 1024];   // 131,072 B
    __shared__ __align__(4) unsigned char s_pack[4 * 256];    //   1,024 B

    const int wg = blockIdx.x, tid = threadIdx.x;
    const int w = tid >> 6, lane = tid & 63;
    const int col = lane & 15, quad = lane >> 4;
    const int bh = w >> 1, p = w & 1;
    unsigned* s_w32 = (unsigned*)s_w;

    // ---- stage W_hh rows -> LDS fp8 x256, XOR-swizzled on 8-B blocks ----
    // row r = g*32+uu -> W_hh[g*1000 + wg*32+uu][k], zero for pad m/k
    for (int idx = tid; idx < 128 * 256; idx += 256) {
        int r = idx >> 8, dw = idx & 255;
        int g = r >> 5, uu = r & 31, m = wg * 32 + uu;
        float4 w4 = make_float4(0.f, 0.f, 0.f, 0.f);
        if (m < NH && dw < 250)
            w4 = *(const float4*)&W_hh[(size_t)(g * NH + m) * NH + dw * 4];
        int p0 = __builtin_amdgcn_cvt_pk_fp8_f32(w4.x * WSCALE, w4.y * WSCALE, 0, false);
        int p1 = __builtin_amdgcn_cvt_pk_fp8_f32(w4.z * WSCALE, w4.w * WSCALE, 0, false);
        unsigned v = ((unsigned)p0 & 0xffffu) | ((unsigned)p1 << 16);
        int kb = dw >> 1;
        int kbs = kb ^ (r & 15);
        s_w32[r * 256 + (kbs << 1) + (dw & 1)] = v;
    }
    // ---- zero h_q[0] slice (this WG's 32 unit-bytes for all 32 b) ----
    {
        int b = tid >> 3, dwi = tid & 7;
        __hip_atomic_store((unsigned*)(h_q + (size_t)b * KHQ + wg * 32 + dwi * 4), 0u,
                           __ATOMIC_RELAXED, __HIP_MEMORY_SCOPE_AGENT);
    }

    // ---- xg prefetch t=0 ----
    s16x4 xcur[4], xnxt[4];
#pragma unroll
    for (int g = 0; g < 4; ++g)
        xcur[g] = *(const s16x4*)&xg[((size_t)(0 * NJ) + wg * 128 + (2 * g + p) * 16 + col) * NB
                                     + bh * 16 + quad * 4];

    gbar(flags, 1u);

    float c[4] = {0.f, 0.f, 0.f, 0.f};
    const int rw = (lane >> 4) * 4;              // quad*4 (batch sub-offset)

    for (int t = 0; t < T_SEQ; ++t) {
        // prefetch next-step xg while this step works
        int tn = (t + 1 < T_SEQ) ? t + 1 : t;
#pragma unroll
        for (int g = 0; g < 4; ++g)
            xnxt[g] = *(const s16x4*)&xg[((size_t)tn * NJ + wg * 128 + (2 * g + p) * 16 + col) * NB
                                         + bh * 16 + quad * 4];

        const unsigned char* hqt = h_q + (size_t)t * NB * KHQ + (size_t)(bh * 16 + col) * KHQ;
        f32x4 acc0 = {0.f, 0.f, 0.f, 0.f};
        f32x4 acc1 = {0.f, 0.f, 0.f, 0.f};
        f32x4 acc2 = {0.f, 0.f, 0.f, 0.f};
        f32x4 acc3 = {0.f, 0.f, 0.f, 0.f};
#pragma unroll
        for (int kc = 0; kc < 32; ++kc) {
            u64 a = __hip_atomic_load((const u64*)(hqt + kc * 32 + quad * 8),
                                      __ATOMIC_RELAXED, __HIP_MEMORY_SCOPE_AGENT);
            int kb = kc * 4 + quad;
            // tile g row = (2g+p)*16 + col; row&15 == col
            u64 b0 = *(const u64*)&s_w[((0 * 2 + p) * 16 + col) * 1024 + ((kb ^ col) << 3)];
            u64 b1 = *(const u64*)&s_w[((1 * 2 + p) * 16 + col) * 1024 + ((kb ^ col) << 3)];
            u64 b2 = *(const u64*)&s_w[((2 * 2 + p) * 16 + col) * 1024 + ((kb ^ col) << 3)];
            u64 b3 = *(const u64*)&s_w[((3 * 2 + p) * 16 + col) * 1024 + ((kb ^ col) << 3)];
            acc0 = __builtin_amdgcn_mfma_f32_16x16x32_fp8_fp8((long)a, (long)b0, acc0, 0, 0, 0);
            acc1 = __builtin_amdgcn_mfma_f32_16x16x32_fp8_fp8((long)a, (long)b1, acc1, 0, 0, 0);
            acc2 = __builtin_amdgcn_mfma_f32_16x16x32_fp8_fp8((long)a, (long)b2, acc2, 0, 0, 0);
            acc3 = __builtin_amdgcn_mfma_f32_16x16x32_fp8_fp8((long)a, (long)b3, acc3, 0, 0, 0);
        }

        // ---- intra-lane epilogue: 4 cells (b = bh*16+rw+r, u = 32wg+16p+col) ----
        float hv[4];
#pragma unroll
        for (int r = 0; r < 4; ++r) {
            float gi = acc0[r] * GSCALE + bf2f((unsigned short)xcur[0][r]);
            float gf = acc1[r] * GSCALE + bf2f((unsigned short)xcur[1][r]);
            float gg = acc2[r] * GSCALE + bf2f((unsigned short)xcur[2][r]);
            float go = acc3[r] * GSCALE + bf2f((unsigned short)xcur[3][r]);
            c[r] = fsig(gf) * c[r] + fsig(gi) * ftanh(gg);
            hv[r] = fsig(go) * ftanh(c[r]);
            // bf16 h for tag_kernel (plain store; flushed at kernel end)
            hs[((size_t)(t + 1) * NB + bh * 16 + rw + r) * HP + wg * 32 + p * 16 + col] = f2bf(hv[r]);
        }
        // ---- pack h -> fp8 bytes via LDS bounce, then u32 atomic stores ----
        {
            int p01 = __builtin_amdgcn_cvt_pk_fp8_f32(hv[0] * HSCALE, hv[1] * HSCALE, 0, false);
            int p23 = __builtin_amdgcn_cvt_pk_fp8_f32(hv[2] * HSCALE, hv[3] * HSCALE, 0, false);
            s_pack[w * 256 + (rw + 0) * 16 + col] = (unsigned char)(p01 & 0xff);
            s_pack[w * 256 + (rw + 1) * 16 + col] = (unsigned char)((p01 >> 8) & 0xff);
            s_pack[w * 256 + (rw + 2) * 16 + col] = (unsigned char)(p23 & 0xff);
            s_pack[w * 256 + (rw + 3) * 16 + col] = (unsigned char)((p23 >> 8) & 0xff);
        }
        __syncthreads();
        {
            int bl = lane >> 2, cb = (lane & 3) * 4;   // 64 dwords per wave
            unsigned v = *(const unsigned*)&s_pack[w * 256 + bl * 16 + cb];
            __hip_atomic_store((unsigned*)(h_q + (size_t)(t + 1) * NB * KHQ
                               + (size_t)(bh * 16 + bl) * KHQ + wg * 32 + p * 16 + cb),
                               v, __ATOMIC_RELAXED, __HIP_MEMORY_SCOPE_AGENT);
        }
#pragma unroll
        for (int g = 0; g < 4; ++g) xcur[g] = xnxt[g];
        if (t < T_SEQ - 1) gbar(flags, (unsigned)(t + 2));
    }
}

// ---------------------------------------------------------------------------
// tag_kernel: tag_space + log_softmax over BATCH axis -> em[t][b][k] (f32)
// ---------------------------------------------------------------------------
__global__ __launch_bounds__(320) void tag_kernel(
    const unsigned short* __restrict__ hs, const float* __restrict__ lin_w,
    const float* __restrict__ lin_b, float* __restrict__ em)
{
    __shared__ float s_lin[NH * NK];
    __shared__ float s_ts[NB * NK];
    __shared__ float s_lse[NK];
    const int t = blockIdx.x, tid = threadIdx.x;
    for (int idx = tid; idx < NH * NK; idx += 320) {
        int e = idx / NK, k = idx - e * NK;
        s_lin[idx] = lin_w[(size_t)k * NH + e];
    }
    __syncthreads();
    if (tid < NB * NK) {
        int b = tid / NK, k = tid - b * NK;
        const unsigned short* hrow = hs + ((size_t)(t + 1) * NB + b) * HP;
        float acc = lin_b[k];
#pragma unroll 4
        for (int e = 0; e < NH; ++e)
            acc += bf2f(hrow[e]) * s_lin[e * NK + k];
        s_ts[b * NK + k] = acc;
    }
    __syncthreads();
    if (tid < NK) {
        float m = -1e30f;
        for (int b = 0; b < NB; ++b) m = fmaxf(m, s_ts[b * NK + tid]);
        float s = 0.f;
        for (int b = 0; b < NB; ++b) s += __expf(s_ts[b * NK + tid] - m);
        s_lse[tid] = m + __logf(s);
    }
    __syncthreads();
    if (tid < NB * NK) {
        int b = tid / NK, k = tid - b * NK;
        em[((size_t)t * NB + b) * NK + k] = s_ts[b * NK + k] - s_lse[k];
    }
}

// ---------------------------------------------------------------------------
// crf_kernel: numerator + alpha recursion + reduction -> out[0]
// ---------------------------------------------------------------------------
__global__ __launch_bounds__(320) void crf_kernel(
    const int* __restrict__ y, const float* __restrict__ em,
    const float* __restrict__ start_trans, const float* __restrict__ end_trans,
    const float* __restrict__ trans, float* __restrict__ out)
{
    __shared__ float s_trans[NK * NK];
    __shared__ float s_alpha[NB * NK];
    __shared__ float s_red[NB];
    const int tid = threadIdx.x;
    if (tid < NK * NK) s_trans[tid] = trans[tid];
    __syncthreads();

    float num = 0.f;
    if (tid < NB) {
        int b = tid, yp = y[b];
        num = start_trans[yp] + em[(size_t)b * NK + yp];
        for (int t = 1; t < T_SEQ; ++t) {
            int yc = y[t * NB + b];
            num += s_trans[yp * NK + yc] + em[((size_t)t * NB + b) * NK + yc];
            yp = yc;
        }
        num += end_trans[yp];
    }

    const int b = tid / NK, k = tid - (tid / NK) * NK;
    if (tid < NB * NK)
        s_alpha[tid] = start_trans[k] + em[(size_t)b * NK + k];
    __syncthreads();

    for (int t = 1; t < T_SEQ; ++t) {
        float nv = 0.f;
        if (tid < NB * NK) {
            float m = -1e30f;
#pragma unroll
            for (int i = 0; i < NK; ++i)
                m = fmaxf(m, s_alpha[b * NK + i] + s_trans[i * NK + k]);
            float s = 0.f;
#pragma unroll
            for (int i = 0; i < NK; ++i)
                s += __expf(s_alpha[b * NK + i] + s_trans[i * NK + k] - m);
            nv = em[((size_t)t * NB + b) * NK + k] + m + __logf(s);
        }
        __syncthreads();
        if (tid < NB * NK) s_alpha[tid] = nv;
        __syncthreads();
    }

    if (tid < NB) {
        float m = -1e30f;
        for (int k2 = 0; k2 < NK; ++k2)
            m = fmaxf(m, s_alpha[tid * NK + k2] + end_trans[k2]);
        float s = 0.f;
        for (int k2 = 0; k2 < NK; ++k2)
            s += __expf(s_alpha[tid * NK + k2] + end_trans[k2] - m);
        s_red[tid] = num - (m + __logf(s));
    }
    __syncthreads();
    if (tid == 0) {
        float tot = 0.f;
        for (int i = 0; i < NB; ++i) tot += s_red[i];
        out[0] = tot;
    }
}

// ---------------------------------------------------------------------------
extern "C" void kernel_launch(void* const* d_in, const int* in_sizes, int n_in,
                              void* d_out, int out_size, void* d_ws, size_t ws_size,
                              hipStream_t stream)
{
    const int*   x           = (const int*)d_in[0];
    const int*   y           = (const int*)d_in[1];
    const float* embed_w     = (const float*)d_in[2];
    const float* W_ih        = (const float*)d_in[3];
    const float* W_hh        = (const float*)d_in[4];
    const float* b_ih        = (const float*)d_in[5];
    const float* b_hh        = (const float*)d_in[6];
    const float* lin_w       = (const float*)d_in[7];
    const float* lin_b       = (const float*)d_in[8];
    const float* start_trans = (const float*)d_in[9];
    const float* end_trans   = (const float*)d_in[10];
    const float* trans       = (const float*)d_in[11];
    float* out = (float*)d_out;

    char* ws = (char*)d_ws;
    unsigned short* xg     = (unsigned short*)(ws);               // 52,428,800 B
    unsigned short* hs     = (unsigned short*)(ws + 52428800);    // 13,172,736 B
    float*          em     = (float*)(ws + 65601536);             //    230,400 B
    unsigned*       flags  = (unsigned*)(ws + 65831936);          //      8,192 B
    float*          biasg  = (float*)(ws + 65840128);             //     16,384 B
    unsigned short* emb_bf = (unsigned short*)(ws + 65856512);    //  4,096,000 B
    unsigned short* wih_bf = (unsigned short*)(ws + 69952512);    //  2,621,440 B
    // h_q overlays emb_bf/wih_bf region (both dead once lstm starts)
    unsigned char*  h_q    = (unsigned char*)(ws + 65856512);     //  6,586,368 B

    prep_emb<<<dim3(T_SEQ), 256, 0, stream>>>(x, embed_w, emb_bf, flags);
    prep_w<<<dim3(64), 256, 0, stream>>>(W_ih, b_ih, b_hh, wih_bf, biasg);
    proj_kernel<<<dim3(64, T_SEQ), 256, 0, stream>>>(emb_bf, wih_bf, biasg, xg);

    lstm_kernel<<<dim3(32), 256, 0, stream>>>(W_hh, xg, hs, h_q, flags);

    tag_kernel<<<dim3(T_SEQ), 320, 0, stream>>>(hs, lin_w, lin_b, em);
    crf_kernel<<<dim3(1), 320, 0, stream>>>(y, em, start_trans, end_trans, trans, out);
}

// Round 7
// 1510.620 us; speedup vs baseline: 1.6860x; 1.4034x over previous
//
#include <hip/hip_runtime.h>

#define T_SEQ 200
#define NB    32
#define NE    300
#define NH    1000
#define NK    9
#define HP    1024          // hs row stride (elements, bf16)
#define NJ    4096          // xg rows per t
#define EPD   320           // padded embed K
#define WSCALE 256.0f
#define HSCALE 16.0f
#define GSCALE (1.0f / (256.0f * 16.0f))

typedef __attribute__((ext_vector_type(4))) float f32x4;
typedef __attribute__((ext_vector_type(8))) short s16x8;
typedef __attribute__((ext_vector_type(4))) short s16x4;
typedef unsigned long long u64;

__device__ __forceinline__ unsigned short f2bf(float f) {
    union { float f; unsigned u; } v; v.f = f;
    unsigned r = v.u + 0x7FFFu + ((v.u >> 16) & 1u);   // RNE
    return (unsigned short)(r >> 16);
}
__device__ __forceinline__ float bf2f(unsigned short h) {
    union { unsigned u; float f; } v; v.u = ((unsigned)h) << 16;
    return v.f;
}
__device__ __forceinline__ float ftanh(float x) {
    float e = __expf(fminf(2.f * x, 80.f));
    return (e - 1.f) / (e + 1.f);
}
__device__ __forceinline__ float fsig(float x) {
    return 1.f / (1.f + __expf(-x));
}

// ---------------------------------------------------------------------------
__global__ __launch_bounds__(256) void prep_emb(
    const int* __restrict__ x, const float* __restrict__ embed_w,
    unsigned short* __restrict__ emb_bf, unsigned* __restrict__ flags)
{
    const int t = blockIdx.x, tid = threadIdx.x;
    if (blockIdx.x == 0) {
        for (int i = tid; i < 2048; i += 256) flags[i] = 0;
    }
    for (int idx = tid; idx < NB * EPD; idx += 256) {
        int b = idx / EPD, e = idx - b * EPD;
        float v = (e < NE) ? embed_w[(size_t)x[t * NB + b] * NE + e] : 0.f;
        emb_bf[((size_t)t * NB + b) * EPD + e] = f2bf(v);
    }
}

// ---------------------------------------------------------------------------
__global__ __launch_bounds__(256) void prep_w(
    const float* __restrict__ W_ih, const float* __restrict__ b_ih,
    const float* __restrict__ b_hh, unsigned short* __restrict__ wih_bf,
    float* __restrict__ biasg)
{
    const int blk = blockIdx.x, tid = threadIdx.x;
    for (int idx = tid; idx < 64 * EPD; idx += 256) {
        int jr = idx / EPD, e = idx - jr * EPD;
        int jp = blk * 64 + jr;
        int wgu = jp >> 7, rr = jp & 127, g = rr >> 5, uu = rr & 31;
        int m = wgu * 32 + uu;
        float v = (m < NH && e < NE) ? W_ih[(size_t)(g * NH + m) * NE + e] : 0.f;
        wih_bf[(size_t)jp * EPD + e] = f2bf(v);
    }
    if (tid < 64) {
        int jp = blk * 64 + tid;
        int wgu = jp >> 7, rr = jp & 127, g = rr >> 5, uu = rr & 31;
        int m = wgu * 32 + uu;
        biasg[jp] = (m < NH) ? (b_ih[g * NH + m] + b_hh[g * NH + m]) : 0.f;
    }
}

// ---------------------------------------------------------------------------
__global__ __launch_bounds__(256) void proj_kernel(
    const unsigned short* __restrict__ emb_bf,
    const unsigned short* __restrict__ wih_bf,
    const float* __restrict__ biasg, unsigned short* __restrict__ xg)
{
    const int jt = blockIdx.x, t = blockIdx.y, tid = threadIdx.x;
    const int w = tid >> 6, lane = tid & 63;
    const int col = lane & 15, quad = lane >> 4;

    const unsigned short* eb = emb_bf + (size_t)t * NB * EPD;
    const unsigned short* wb = wih_bf + (size_t)(jt * 64 + w * 16 + col) * EPD;
    const unsigned short* ea0 = eb + (size_t)col * EPD;
    const unsigned short* ea1 = eb + (size_t)(16 + col) * EPD;

    f32x4 acc0 = {0.f, 0.f, 0.f, 0.f};
    f32x4 acc1 = {0.f, 0.f, 0.f, 0.f};
#pragma unroll
    for (int kc = 0; kc < EPD / 32; ++kc) {
        int ko = kc * 32 + quad * 8;
        s16x8 a0 = *(const s16x8*)&ea0[ko];
        s16x8 a1 = *(const s16x8*)&ea1[ko];
        s16x8 bb = *(const s16x8*)&wb[ko];
        acc0 = __builtin_amdgcn_mfma_f32_16x16x32_bf16(a0, bb, acc0, 0, 0, 0);
        acc1 = __builtin_amdgcn_mfma_f32_16x16x32_bf16(a1, bb, acc1, 0, 0, 0);
    }
    const int jp = jt * 64 + w * 16 + col;
    const float bi = biasg[jp];
    size_t base = ((size_t)t * NJ + jp) * NB;
    s16x4 p0, p1;
#pragma unroll
    for (int r = 0; r < 4; ++r) {
        p0[r] = (short)f2bf(acc0[r] + bi);
        p1[r] = (short)f2bf(acc1[r] + bi);
    }
    *(s16x4*)&xg[base + quad * 4]      = p0;
    *(s16x4*)&xg[base + 16 + quad * 4] = p1;
}

// ---------------------------------------------------------------------------
// flag barrier, hot spin (no sleep). syncthreads drains vmcnt (h_q stores
// MALL-ack'd) before publish.
// ---------------------------------------------------------------------------
__device__ __forceinline__ void gbar(unsigned* flags, unsigned phase) {
    __syncthreads();
    const int tid = threadIdx.x;
    if (tid < 64) {
        if (tid == 0)
            __hip_atomic_store(&flags[blockIdx.x], phase,
                               __ATOMIC_RELAXED, __HIP_MEMORY_SCOPE_AGENT);
        bool done;
        do {
            unsigned v = (tid < 32)
                ? __hip_atomic_load(&flags[tid], __ATOMIC_RELAXED,
                                    __HIP_MEMORY_SCOPE_AGENT)
                : phase;
            done = (bool)__all((int)(v >= phase));
        } while (!done);
    }
    __syncthreads();
    __builtin_amdgcn_fence(__ATOMIC_ACQUIRE, "workgroup");  // order-only
}

// ---------------------------------------------------------------------------
// lstm: 32 WGs x 256 thr. WG wg owns units [32wg,32wg+32) == K-chunk wg.
// h_q layout [t][kc(32)][b(32)][8B] -> consumer wave loads 512-B bursts.
// h stores: agent-relaxed atomics (write-through). h loads: PLAIN dwordx2
// (fresh addresses each step; L2 clean at first touch).
// ---------------------------------------------------------------------------
__global__ __launch_bounds__(256, 1) void lstm_kernel(
    const float* __restrict__ W_hh,
    const unsigned short* __restrict__ xg,
    unsigned short* __restrict__ hs,
    unsigned char* __restrict__ h_q,
    unsigned* __restrict__ flags)
{
    __shared__ __align__(16) unsigned char s_w[128 * 1024];   // 131,072 B
    __shared__ __align__(4) unsigned char s_pack[1024];       // [b(32)][u(32)]

    const int wg = blockIdx.x, tid = threadIdx.x;
    const int w = tid >> 6, lane = tid & 63;
    const int col = lane & 15, quad = lane >> 4;
    const int bh = w >> 1, p = w & 1;
    unsigned* s_w32 = (unsigned*)s_w;
    unsigned* s_pack32 = (unsigned*)s_pack;

    // ---- stage W_hh -> LDS fp8 x256, XOR-swizzled on 8-B blocks ----
    for (int idx = tid; idx < 128 * 256; idx += 256) {
        int r = idx >> 8, dw = idx & 255;
        int g = r >> 5, uu = r & 31, m = wg * 32 + uu;
        float4 w4 = make_float4(0.f, 0.f, 0.f, 0.f);
        if (m < NH && dw < 250)
            w4 = *(const float4*)&W_hh[(size_t)(g * NH + m) * NH + dw * 4];
        int p0 = __builtin_amdgcn_cvt_pk_fp8_f32(w4.x * WSCALE, w4.y * WSCALE, 0, false);
        int p1 = __builtin_amdgcn_cvt_pk_fp8_f32(w4.z * WSCALE, w4.w * WSCALE, 0, false);
        unsigned v = ((unsigned)p0 & 0xffffu) | ((unsigned)p1 << 16);
        int kb = dw >> 1;
        int kbs = kb ^ (r & 15);
        s_w32[r * 256 + (kbs << 1) + (dw & 1)] = v;
    }
    // ---- zero h_q page 0, this WG's K-chunk ----
    __hip_atomic_store((unsigned*)(h_q + (size_t)wg * 1024 + tid * 4), 0u,
                       __ATOMIC_RELAXED, __HIP_MEMORY_SCOPE_AGENT);

    // ---- xg prefetch t=0 ----
    s16x4 xcur[4], xnxt[4];
#pragma unroll
    for (int g = 0; g < 4; ++g)
        xcur[g] = *(const s16x4*)&xg[((size_t)0 * NJ + wg * 128 + (2 * g + p) * 16 + col) * NB
                                     + bh * 16 + quad * 4];

    gbar(flags, 1u);

    float c[4] = {0.f, 0.f, 0.f, 0.f};
    const int rw = quad * 4;

    for (int t = 0; t < T_SEQ; ++t) {
        int tn = (t + 1 < T_SEQ) ? t + 1 : t;
#pragma unroll
        for (int g = 0; g < 4; ++g)
            xnxt[g] = *(const s16x4*)&xg[((size_t)tn * NJ + wg * 128 + (2 * g + p) * 16 + col) * NB
                                         + bh * 16 + quad * 4];

        // ---- plain wide h loads: 32 x dwordx2, all in flight ----
        const unsigned char* pb = h_q + (size_t)t * 32768
                                + (size_t)(bh * 16 + col) * 32 + quad * 8;
        u64 a[32];
#pragma unroll
        for (int kc = 0; kc < 32; ++kc)
            a[kc] = *(const u64*)(pb + kc * 1024);

        f32x4 acc0 = {0.f, 0.f, 0.f, 0.f};
        f32x4 acc1 = {0.f, 0.f, 0.f, 0.f};
        f32x4 acc2 = {0.f, 0.f, 0.f, 0.f};
        f32x4 acc3 = {0.f, 0.f, 0.f, 0.f};
#pragma unroll
        for (int kc = 0; kc < 32; ++kc) {
            int kb = kc * 4 + quad;
            u64 b0 = *(const u64*)&s_w[((0 * 2 + p) * 16 + col) * 1024 + ((kb ^ col) << 3)];
            u64 b1 = *(const u64*)&s_w[((1 * 2 + p) * 16 + col) * 1024 + ((kb ^ col) << 3)];
            u64 b2 = *(const u64*)&s_w[((2 * 2 + p) * 16 + col) * 1024 + ((kb ^ col) << 3)];
            u64 b3 = *(const u64*)&s_w[((3 * 2 + p) * 16 + col) * 1024 + ((kb ^ col) << 3)];
            acc0 = __builtin_amdgcn_mfma_f32_16x16x32_fp8_fp8((long)a[kc], (long)b0, acc0, 0, 0, 0);
            acc1 = __builtin_amdgcn_mfma_f32_16x16x32_fp8_fp8((long)a[kc], (long)b1, acc1, 0, 0, 0);
            acc2 = __builtin_amdgcn_mfma_f32_16x16x32_fp8_fp8((long)a[kc], (long)b2, acc2, 0, 0, 0);
            acc3 = __builtin_amdgcn_mfma_f32_16x16x32_fp8_fp8((long)a[kc], (long)b3, acc3, 0, 0, 0);
        }

        // ---- epilogue: 4 cells (b = bh*16+rw+r, u = 16p+col) ----
        float hv[4];
#pragma unroll
        for (int r = 0; r < 4; ++r) {
            float gi = acc0[r] * GSCALE + bf2f((unsigned short)xcur[0][r]);
            float gf = acc1[r] * GSCALE + bf2f((unsigned short)xcur[1][r]);
            float gg = acc2[r] * GSCALE + bf2f((unsigned short)xcur[2][r]);
            float go = acc3[r] * GSCALE + bf2f((unsigned short)xcur[3][r]);
            c[r] = fsig(gf) * c[r] + fsig(gi) * ftanh(gg);
            hv[r] = fsig(go) * ftanh(c[r]);
        }
        // pack fp8 into s_pack[b][u]
        {
            int p01 = __builtin_amdgcn_cvt_pk_fp8_f32(hv[0] * HSCALE, hv[1] * HSCALE, 0, false);
            int p23 = __builtin_amdgcn_cvt_pk_fp8_f32(hv[2] * HSCALE, hv[3] * HSCALE, 0, false);
            s_pack[(bh * 16 + rw + 0) * 32 + p * 16 + col] = (unsigned char)(p01 & 0xff);
            s_pack[(bh * 16 + rw + 1) * 32 + p * 16 + col] = (unsigned char)((p01 >> 8) & 0xff);
            s_pack[(bh * 16 + rw + 2) * 32 + p * 16 + col] = (unsigned char)(p23 & 0xff);
            s_pack[(bh * 16 + rw + 3) * 32 + p * 16 + col] = (unsigned char)((p23 >> 8) & 0xff);
        }
        __syncthreads();
        // coalesced 1024-B atomic store of this WG's K-chunk
        __hip_atomic_store((unsigned*)(h_q + (size_t)(t + 1) * 32768 + (size_t)wg * 1024 + tid * 4),
                           s_pack32[tid], __ATOMIC_RELAXED, __HIP_MEMORY_SCOPE_AGENT);

        if (t < T_SEQ - 1) gbar(flags, (unsigned)(t + 2));

        // bf16 h for tag path (plain stores, drain at next barrier / kernel end)
#pragma unroll
        for (int r = 0; r < 4; ++r)
            hs[((size_t)(t + 1) * NB + bh * 16 + rw + r) * HP + wg * 32 + p * 16 + col] = f2bf(hv[r]);
#pragma unroll
        for (int g = 0; g < 4; ++g) xcur[g] = xnxt[g];
    }
}

// ---------------------------------------------------------------------------
// tag_gemm: ts[m][n] = hs[m+NB] . lin_w[n]  (M=6400, N=16 pad, K=1024 pad)
// one wave per 16-row tile
// ---------------------------------------------------------------------------
__global__ __launch_bounds__(64) void tag_gemm(
    const unsigned short* __restrict__ hs, const float* __restrict__ lin_w,
    float* __restrict__ ts)
{
    const int m0 = blockIdx.x * 16, lane = threadIdx.x;
    const int col = lane & 15, quad = lane >> 4;
    const unsigned short* ar = hs + (size_t)(NB + m0 + col) * HP;

    f32x4 acc = {0.f, 0.f, 0.f, 0.f};
#pragma unroll 8
    for (int kc = 0; kc < 32; ++kc) {
        int k0 = kc * 32 + quad * 8;
        s16x8 av = *(const s16x8*)&ar[k0];
        s16x8 bv;
        if (col < NK && kc < 31) {
            const float* lw = &lin_w[(size_t)col * NH + k0];
            float4 f0 = *(const float4*)lw;
            float4 f1 = *(const float4*)(lw + 4);
            bv[0] = (short)f2bf(f0.x); bv[1] = (short)f2bf(f0.y);
            bv[2] = (short)f2bf(f0.z); bv[3] = (short)f2bf(f0.w);
            bv[4] = (short)f2bf(f1.x); bv[5] = (short)f2bf(f1.y);
            bv[6] = (short)f2bf(f1.z); bv[7] = (short)f2bf(f1.w);
        } else {
#pragma unroll
            for (int j = 0; j < 8; ++j) {
                int k = k0 + j;
                float v = (col < NK && k < NH) ? lin_w[(size_t)col * NH + k] : 0.f;
                bv[j] = (short)f2bf(v);
            }
        }
        acc = __builtin_amdgcn_mfma_f32_16x16x32_bf16(av, bv, acc, 0, 0, 0);
    }
#pragma unroll
    for (int r = 0; r < 4; ++r)
        ts[(size_t)(m0 + quad * 4 + r) * 16 + col] = acc[r];
}

// ---------------------------------------------------------------------------
// em_kernel: emissions[t][b][k] = (ts + lin_b) - logsumexp over BATCH axis
// ---------------------------------------------------------------------------
__global__ __launch_bounds__(320) void em_kernel(
    const float* __restrict__ ts, const float* __restrict__ lin_b,
    float* __restrict__ em)
{
    __shared__ float s_ts[NB * NK];
    __shared__ float s_lse[NK];
    const int t = blockIdx.x, tid = threadIdx.x;
    float val = 0.f;
    int b = tid / NK, k = tid - b * NK;
    if (tid < NB * NK) {
        val = ts[(size_t)(t * NB + b) * 16 + k] + lin_b[k];
        s_ts[b * NK + k] = val;
    }
    __syncthreads();
    if (tid < NK) {
        float m = -1e30f;
        for (int bb = 0; bb < NB; ++bb) m = fmaxf(m, s_ts[bb * NK + tid]);
        float s = 0.f;
        for (int bb = 0; bb < NB; ++bb) s += __expf(s_ts[bb * NK + tid] - m);
        s_lse[tid] = m + __logf(s);
    }
    __syncthreads();
    if (tid < NB * NK)
        em[((size_t)t * NB + b) * NK + k] = val - s_lse[k];
}

// ---------------------------------------------------------------------------
__global__ __launch_bounds__(320) void crf_kernel(
    const int* __restrict__ y, const float* __restrict__ em,
    const float* __restrict__ start_trans, const float* __restrict__ end_trans,
    const float* __restrict__ trans, float* __restrict__ out)
{
    __shared__ float s_trans[NK * NK];
    __shared__ float s_alpha[NB * NK];
    __shared__ float s_red[NB];
    const int tid = threadIdx.x;
    if (tid < NK * NK) s_trans[tid] = trans[tid];
    __syncthreads();

    float num = 0.f;
    if (tid < NB) {
        int b = tid, yp = y[b];
        num = start_trans[yp] + em[(size_t)b * NK + yp];
        for (int t = 1; t < T_SEQ; ++t) {
            int yc = y[t * NB + b];
            num += s_trans[yp * NK + yc] + em[((size_t)t * NB + b) * NK + yc];
            yp = yc;
        }
        num += end_trans[yp];
    }

    const int b = tid / NK, k = tid - (tid / NK) * NK;
    if (tid < NB * NK)
        s_alpha[tid] = start_trans[k] + em[(size_t)b * NK + k];
    __syncthreads();

    for (int t = 1; t < T_SEQ; ++t) {
        float nv = 0.f;
        if (tid < NB * NK) {
            float m = -1e30f;
#pragma unroll
            for (int i = 0; i < NK; ++i)
                m = fmaxf(m, s_alpha[b * NK + i] + s_trans[i * NK + k]);
            float s = 0.f;
#pragma unroll
            for (int i = 0; i < NK; ++i)
                s += __expf(s_alpha[b * NK + i] + s_trans[i * NK + k] - m);
            nv = em[((size_t)t * NB + b) * NK + k] + m + __logf(s);
        }
        __syncthreads();
        if (tid < NB * NK) s_alpha[tid] = nv;
        __syncthreads();
    }

    if (tid < NB) {
        float m = -1e30f;
        for (int k2 = 0; k2 < NK; ++k2)
            m = fmaxf(m, s_alpha[tid * NK + k2] + end_trans[k2]);
        float s = 0.f;
        for (int k2 = 0; k2 < NK; ++k2)
            s += __expf(s_alpha[tid * NK + k2] + end_trans[k2] - m);
        s_red[tid] = num - (m + __logf(s));
    }
    __syncthreads();
    if (tid == 0) {
        float tot = 0.f;
        for (int i = 0; i < NB; ++i) tot += s_red[i];
        out[0] = tot;
    }
}

// ---------------------------------------------------------------------------
extern "C" void kernel_launch(void* const* d_in, const int* in_sizes, int n_in,
                              void* d_out, int out_size, void* d_ws, size_t ws_size,
                              hipStream_t stream)
{
    const int*   x           = (const int*)d_in[0];
    const int*   y           = (const int*)d_in[1];
    const float* embed_w     = (const float*)d_in[2];
    const float* W_ih        = (const float*)d_in[3];
    const float* W_hh        = (const float*)d_in[4];
    const float* b_ih        = (const float*)d_in[5];
    const float* b_hh        = (const float*)d_in[6];
    const float* lin_w       = (const float*)d_in[7];
    const float* lin_b       = (const float*)d_in[8];
    const float* start_trans = (const float*)d_in[9];
    const float* end_trans   = (const float*)d_in[10];
    const float* trans       = (const float*)d_in[11];
    float* out = (float*)d_out;

    char* ws = (char*)d_ws;
    unsigned short* xg     = (unsigned short*)(ws);               // 52,428,800 B
    float*          ts     = (float*)(ws);                        // aliases xg (dead post-lstm)
    unsigned short* hs     = (unsigned short*)(ws + 52428800);    // 13,172,736 B
    float*          em     = (float*)(ws + 65601536);             //    230,400 B
    unsigned*       flags  = (unsigned*)(ws + 65831936);          //      8,192 B
    float*          biasg  = (float*)(ws + 65840128);             //     16,384 B
    unsigned short* emb_bf = (unsigned short*)(ws + 65856512);    //  4,096,000 B
    unsigned short* wih_bf = (unsigned short*)(ws + 69952512);    //  2,621,440 B
    unsigned char*  h_q    = (unsigned char*)(ws + 65856512);     //  6,586,368 B (overlay)

    prep_emb<<<dim3(T_SEQ), 256, 0, stream>>>(x, embed_w, emb_bf, flags);
    prep_w<<<dim3(64), 256, 0, stream>>>(W_ih, b_ih, b_hh, wih_bf, biasg);
    proj_kernel<<<dim3(64, T_SEQ), 256, 0, stream>>>(emb_bf, wih_bf, biasg, xg);

    lstm_kernel<<<dim3(32), 256, 0, stream>>>(W_hh, xg, hs, h_q, flags);

    tag_gemm<<<dim3(400), 64, 0, stream>>>(hs, lin_w, ts);
    em_kernel<<<dim3(T_SEQ), 320, 0, stream>>>(ts, lin_b, em);
    crf_kernel<<<dim3(1), 320, 0, stream>>>(y, em, start_trans, end_trans, trans, out);
}